// Round 16
// baseline (205.136 us; speedup 1.0000x reference)
//
#include <hip/hip_runtime.h>
#include <hip/hip_bf16.h>
#include <stdint.h>

typedef unsigned short u16;
typedef u16 u16x4 __attribute__((ext_vector_type(4)));
typedef unsigned u32x4 __attribute__((ext_vector_type(4)));
typedef __bf16 bf16x8 __attribute__((ext_vector_type(8)));
typedef float f32x4 __attribute__((ext_vector_type(4)));
typedef float f32x16 __attribute__((ext_vector_type(16)));

#define DEVI __device__ __forceinline__

DEVI u16 f2b(float f) {
  __hip_bfloat16 h = __float2bfloat16(f);
  return __builtin_bit_cast(u16, h);
}

DEVI unsigned pk2(float lo, float hi) {
  return (unsigned)f2b(lo) | ((unsigned)f2b(hi) << 16);
}

DEVI float unpk_lo(unsigned t) { return __builtin_bit_cast(float, t << 16); }
DEVI float unpk_hi(unsigned t) { return __builtin_bit_cast(float, t & 0xffff0000u); }

DEVI f32x4 mfma16(bf16x8 a, bf16x8 b, f32x4 c) {
  return __builtin_amdgcn_mfma_f32_16x16x32_bf16(a, b, c, 0, 0, 0);
}

DEVI f32x16 mfma32(bf16x8 a, bf16x8 b, f32x16 c) {
  return __builtin_amdgcn_mfma_f32_32x32x16_bf16(a, b, c, 0, 0, 0);
}

DEVI void gld_lds16(const u16* g, u16* l) {
  __builtin_amdgcn_global_load_lds(
      (const __attribute__((address_space(1))) unsigned int*)g,
      (__attribute__((address_space(3))) unsigned int*)l, 16, 0, 0);
}

// ---------------- prep: rope table (blocks 0..8191) + cvt (8192..26623) ----
__global__ void prep(const float4* __restrict__ x, const float4* __restrict__ wq,
                     const float4* __restrict__ wk, const float4* __restrict__ wv,
                     const float4* __restrict__ wo,
                     u16x4* __restrict__ xb, u16x4* __restrict__ wqb,
                     u16x4* __restrict__ wkb, u16x4* __restrict__ wvb,
                     u16x4* __restrict__ wob, unsigned* __restrict__ csT) {
  long bid = blockIdx.x;
  if (bid < 8192) {
    int i = (int)bid * 256 + threadIdx.x;
    int s = i >> 10, p = i & 1023;
    float freq = exp2f((float)p * -0.012976281620653759f);
    float ang = (float)s * freq;
    float sv, cv;
    __sincosf(ang, &sv, &cv);
    csT[i] = pk2(cv, sv);
    return;
  }
  long i = (bid - 8192) * 256 + threadIdx.x;
  const float4* src; u16x4* dst; long o;
  if (i < 2097152)      { src = x;  dst = xb;  o = i; }
  else if (i < 3145728) { src = wq; dst = wqb; o = i - 2097152; }
  else if (i < 3407872) { src = wk; dst = wkb; o = i - 3145728; }
  else if (i < 3670016) { src = wv; dst = wvb; o = i - 3407872; }
  else                  { src = wo; dst = wob; o = i - 3670016; }
  float4 v = src[o];
  u16x4 r = { f2b(v.x), f2b(v.y), f2b(v.z), f2b(v.w) };
  dst[o] = r;
}

// ---------------- fused QKV GEMM: 256x256, BK=64, 4-phase fine interleave --
// LDS 128KB: 2 buf x {A-k0,A-k1,B-k0,B-k1} 16KB regions (k-half split).
// Per tile t: q0 {rd k0 frags(mi0-3,B) | stage k1(t+1)} q1 {rd A4-7 k0}
// q2 {rd k1 frags | stage k0(t+2)} q3 {rd A4-7 k1; vmcnt(4) before barrier}.
// Swizzle: region slot c holds chunk c^(r&3) -> conflict-free b128 reads.
__global__ __launch_bounds__(512)
void gemm_qkv(const u16* __restrict__ A, const u16* __restrict__ wq,
              const u16* __restrict__ wk, const u16* __restrict__ wv,
              const unsigned* __restrict__ csT, u16* __restrict__ Qh,
              u16* __restrict__ Kh, u16* __restrict__ Vtp) {
  __shared__ __align__(16) u16 lds[2][32768];
  const int tid = threadIdx.x;
  const int lane = tid & 63;
  const int w = tid >> 6;               // 0..7
  const int wr = w >> 2, wc = w & 3;    // 2M x 4N waves
  const int x = blockIdx.x, m0 = blockIdx.y << 8, n0 = x << 8;
  const int K = 2048;

  const u16* Bw;
  int mode;
  if (x < 8)       { Bw = wq + (size_t)n0 * K;          mode = 0; }
  else if (x < 10) { Bw = wk + (size_t)(n0 - 2048) * K; mode = 1; }
  else             { Bw = wv + (size_t)(n0 - 2560) * K; mode = 2; }

  const int sr = tid >> 2;              // 0..127 (staging row)
  const int ckoff = ((tid & 3) ^ (sr & 3)) << 3;   // swizzled global chunk
  const int p_ = sr & 63, p4 = p_ >> 4, pl = p_ & 15;
  const int prow = (sr & ~63) | (pl << 1) | (p4 & 1) | ((p4 & 2) << 4);
  const int bsrc = (mode == 2) ? sr : prow;        // rope-pair row permute
  const int dsto = tid << 3;

  f32x4 acc[8][4] = {};
  const int nk = 32;                    // 2048 / 64

#define STG(ts, kh)                                                       \
  {                                                                       \
    u16* bb_ = &lds[(ts) & 1][((kh) << 13) + dsto];                       \
    const int kc_ = ((ts) << 6) + ((kh) << 5) + ckoff;                    \
    gld_lds16(A + (size_t)(m0 + sr) * K + kc_, bb_);                      \
    gld_lds16(A + (size_t)(m0 + sr + 128) * K + kc_, bb_ + 4096);         \
    gld_lds16(Bw + (size_t)bsrc * K + kc_, bb_ + 16384);                  \
    gld_lds16(Bw + (size_t)(bsrc + 128) * K + kc_, bb_ + 20480);          \
  }

  // prologue: k0(0), k1(0), k0(1); drain to last pair; all-waves sync
  STG(0, 0);
  STG(0, 1);
  STG(1, 0);
  asm volatile("s_waitcnt vmcnt(4)" ::: "memory");
  __builtin_amdgcn_sched_barrier(0);
  __builtin_amdgcn_s_barrier();

  const int l15 = lane & 15;
  const int lg = lane >> 4;
  const int slotR = (lg ^ (l15 & 3)) << 3;
  const int aoff = (((wr << 7) + l15) << 5) + slotR;           // + mi*512 + kh*8192
  const int boff = 16384 + (((wc << 6) + l15) << 5) + slotR;   // + ni*512 + kh*8192

  for (int t = 0; t < nk; ++t) {
    const u16* bb = lds[t & 1];
    const int ts1 = (t + 1 < nk) ? t + 1 : nk - 1;
    const int ts2 = (t + 2 < nk) ? t + 2 : nk - 1;
    bf16x8 a0[4], a1[4], bf[4];

    // ---- q0: k0 frags (A mi0-3, B ni0-3); stage k1(ts1) ----
#pragma unroll
    for (int mi = 0; mi < 4; ++mi) a0[mi] = *(const bf16x8*)&bb[aoff + mi * 512];
#pragma unroll
    for (int ni = 0; ni < 4; ++ni) bf[ni] = *(const bf16x8*)&bb[boff + ni * 512];
    STG(ts1, 1);
    __builtin_amdgcn_s_barrier();
    __builtin_amdgcn_sched_barrier(0);
    __builtin_amdgcn_s_setprio(1);
#pragma unroll
    for (int mi = 0; mi < 4; ++mi)
#pragma unroll
      for (int ni = 0; ni < 4; ++ni)
        acc[mi][ni] = mfma16(a0[mi], bf[ni], acc[mi][ni]);
    __builtin_amdgcn_s_setprio(0);
    __builtin_amdgcn_sched_barrier(0);
    __builtin_amdgcn_s_barrier();

    // ---- q1: A mi4-7 k0 ----
#pragma unroll
    for (int mi = 0; mi < 4; ++mi) a1[mi] = *(const bf16x8*)&bb[aoff + (mi + 4) * 512];
    __builtin_amdgcn_s_barrier();
    __builtin_amdgcn_sched_barrier(0);
    __builtin_amdgcn_s_setprio(1);
#pragma unroll
    for (int mi = 0; mi < 4; ++mi)
#pragma unroll
      for (int ni = 0; ni < 4; ++ni)
        acc[mi + 4][ni] = mfma16(a1[mi], bf[ni], acc[mi + 4][ni]);
    __builtin_amdgcn_s_setprio(0);
    __builtin_amdgcn_sched_barrier(0);
    __builtin_amdgcn_s_barrier();

    // ---- q2: k1 frags; stage k0(ts2) ----
#pragma unroll
    for (int mi = 0; mi < 4; ++mi) a0[mi] = *(const bf16x8*)&bb[aoff + 8192 + mi * 512];
#pragma unroll
    for (int ni = 0; ni < 4; ++ni) bf[ni] = *(const bf16x8*)&bb[boff + 8192 + ni * 512];
    STG(ts2, 0);
    __builtin_amdgcn_s_barrier();
    __builtin_amdgcn_sched_barrier(0);
    __builtin_amdgcn_s_setprio(1);
#pragma unroll
    for (int mi = 0; mi < 4; ++mi)
#pragma unroll
      for (int ni = 0; ni < 4; ++ni)
        acc[mi][ni] = mfma16(a0[mi], bf[ni], acc[mi][ni]);
    __builtin_amdgcn_s_setprio(0);
    __builtin_amdgcn_sched_barrier(0);
    __builtin_amdgcn_s_barrier();

    // ---- q3: A mi4-7 k1; tile-boundary drain: vmcnt BEFORE barrier ----
#pragma unroll
    for (int mi = 0; mi < 4; ++mi) a1[mi] = *(const bf16x8*)&bb[aoff + 8192 + (mi + 4) * 512];
    __builtin_amdgcn_s_barrier();
    __builtin_amdgcn_sched_barrier(0);
    __builtin_amdgcn_s_setprio(1);
#pragma unroll
    for (int mi = 0; mi < 4; ++mi)
#pragma unroll
      for (int ni = 0; ni < 4; ++ni)
        acc[mi + 4][ni] = mfma16(a1[mi], bf[ni], acc[mi + 4][ni]);
    __builtin_amdgcn_s_setprio(0);
    asm volatile("s_waitcnt vmcnt(4)" ::: "memory");
    __builtin_amdgcn_sched_barrier(0);
    __builtin_amdgcn_s_barrier();
  }
  asm volatile("s_waitcnt vmcnt(0)" ::: "memory");
#undef STG

  const int crow = (lane >> 4) << 2;
  if (mode == 0) {
    const float SCL = 0.022097086912079608f * 1.4426950408889634f;  // /sqrt(2048)*log2e
    const int h = (x << 1) + (wc >> 1);
    const int hd0 = ((wc & 1) << 6) + (l15 << 1);
    const int tb = (h << 6) + ((wc & 1) << 5) + l15;
#pragma unroll
    for (int mi = 0; mi < 8; ++mi)
#pragma unroll
      for (int rr = 0; rr < 4; ++rr) {
        int row = m0 + (wr << 7) + (mi << 4) + crow + rr;
        int s = row & 2047, b = row >> 11;
        unsigned tA = csT[(s << 10) + tb];
        unsigned tB = csT[(s << 10) + tb + 16];
        float cAc = unpk_lo(tA), cAs = unpk_hi(tA);
        float cBc = unpk_lo(tB), cBs = unpk_hi(tB);
        float v0 = acc[mi][0][rr], v1 = acc[mi][1][rr];
        float v2 = acc[mi][2][rr], v3 = acc[mi][3][rr];
        unsigned lo = pk2((v0 * cAc - v1 * cAs) * SCL, (v0 * cAs + v1 * cAc) * SCL);
        unsigned hi = pk2((v2 * cBc - v3 * cBs) * SCL, (v2 * cBs + v3 * cBc) * SCL);
        u16* dst = &Qh[((size_t)(b * 16 + h) * 2048 + s) * 128 + hd0];
        *(unsigned*)dst = lo;
        *(unsigned*)(dst + 32) = hi;
      }
  } else if (mode == 1) {
    const int kvh = ((x - 8) << 1) + (wc >> 1);
    const int hd0 = ((wc & 1) << 6) + (l15 << 1);
#pragma unroll
    for (int mi = 0; mi < 8; ++mi)
#pragma unroll
      for (int rr = 0; rr < 4; ++rr) {
        int row = m0 + (wr << 7) + (mi << 4) + crow + rr;
        int s = row & 2047, b = row >> 11;
        float v0 = acc[mi][0][rr], v1 = acc[mi][1][rr];
        float v2 = acc[mi][2][rr], v3 = acc[mi][3][rr];
#pragma unroll
        for (int g = 0; g < 4; ++g) {
          int h = (kvh << 2) + g;
          int tb = (h << 6) + ((wc & 1) << 5) + l15;
          unsigned tA = csT[(s << 10) + tb];
          unsigned tB = csT[(s << 10) + tb + 16];
          float cAc = unpk_lo(tA), cAs = unpk_hi(tA);
          float cBc = unpk_lo(tB), cBs = unpk_hi(tB);
          unsigned lo = pk2(v0 * cAc - v1 * cAs, v0 * cAs + v1 * cAc);
          unsigned hi = pk2(v2 * cBc - v3 * cBs, v2 * cBs + v3 * cBc);
          u16* dst = &Kh[((size_t)(b * 16 + h) * 2048 + s) * 128 + hd0];
          *(unsigned*)dst = lo;
          *(unsigned*)(dst + 32) = hi;
        }
      }
  } else {
#pragma unroll
    for (int mi = 0; mi < 8; ++mi) {
      int sg = m0 + (wr << 7) + (mi << 4) + crow;
      int b = sg >> 11, s = sg & 2047;
#pragma unroll
      for (int ni = 0; ni < 4; ++ni) {
        int n = ((x - 10) << 8) + (wc << 6) + (ni << 4) + l15;
        u16x4 pk = { f2b(acc[mi][ni][0]), f2b(acc[mi][ni][1]),
                     f2b(acc[mi][ni][2]), f2b(acc[mi][ni][3]) };
        *(u16x4*)&Vtp[((size_t)((b << 2) + (n >> 7)) * 128 + (n & 127)) * 2048 + s] = pk;
      }
    }
  }
}

// ---------------- O-projection GEMM: 128x128, 2-buf sync, swizzled, 512 blk
__global__ __launch_bounds__(256)
void gemm_bt(const u16* __restrict__ A, const u16* __restrict__ Bw,
             float* __restrict__ C, int M, int N, int K) {
  __shared__ __align__(16) u16 lds[2][2][4096];
  const int tid = threadIdx.x;
  const int lane = tid & 63;
  const int w = tid >> 6;
  const int wr = w >> 1, wc = w & 1;
  const int m0 = blockIdx.y << 7, n0 = blockIdx.x << 7;

  const int srow = tid >> 2;
  const int cs = (tid & 3) ^ ((srow >> 1) & 3);
  const u16* ga0 = A + (size_t)(m0 + srow) * K + (cs << 3);
  const u16* gb0 = Bw + (size_t)(n0 + srow) * K + (cs << 3);
  const size_t rstep = (size_t)64 * K;

  f32x4 acc[4][4] = {};
  const int nk = K >> 5;
  int cur = 0;

  {
    u16* la = &lds[0][0][tid << 3];
    u16* lb = &lds[0][1][tid << 3];
    gld_lds16(ga0, la);
    gld_lds16(ga0 + rstep, la + 2048);
    gld_lds16(gb0, lb);
    gld_lds16(gb0 + rstep, lb + 2048);
  }
  __syncthreads();

  const int l15 = lane & 15;
  const int lg = lane >> 4;
  const int ch8 = (lg ^ ((l15 >> 1) & 3)) << 3;
  const int abase = (((wr << 6) + l15) << 5) + ch8;
  const int bbase = (((wc << 6) + l15) << 5) + ch8;

  for (int kt = 0; kt < nk; ++kt) {
    if (kt + 1 < nk) {
      const u16* ga = ga0 + ((size_t)(kt + 1) << 5);
      const u16* gb = gb0 + ((size_t)(kt + 1) << 5);
      u16* la = &lds[cur ^ 1][0][tid << 3];
      u16* lb = &lds[cur ^ 1][1][tid << 3];
      gld_lds16(ga, la);
      gld_lds16(ga + rstep, la + 2048);
      gld_lds16(gb, lb);
      gld_lds16(gb + rstep, lb + 2048);
    }
    const u16* la = &lds[cur][0][0];
    const u16* lb = &lds[cur][1][0];
    bf16x8 af[4], bfr[4];
#pragma unroll
    for (int mi = 0; mi < 4; ++mi)
      af[mi] = *(const bf16x8*)&la[abase + (mi << 9)];
#pragma unroll
    for (int ni = 0; ni < 4; ++ni)
      bfr[ni] = *(const bf16x8*)&lb[bbase + (ni << 9)];
#pragma unroll
    for (int mi = 0; mi < 4; ++mi)
#pragma unroll
      for (int ni = 0; ni < 4; ++ni)
        acc[mi][ni] = mfma16(af[mi], bfr[ni], acc[mi][ni]);
    __syncthreads();
    cur ^= 1;
  }

  const int crow = (lane >> 4) << 2;
#pragma unroll
  for (int mi = 0; mi < 4; ++mi) {
    int row = m0 + (wr << 6) + (mi << 4) + crow;
#pragma unroll
    for (int ni = 0; ni < 4; ++ni) {
      int col = n0 + (wc << 6) + (ni << 4) + l15;
#pragma unroll
      for (int rr = 0; rr < 4; ++rr)
        C[(size_t)(row + rr) * N + col] = acc[mi][ni][rr];
    }
  }
}

// ---------------- flash attention: counted-vmcnt 3-buffer pipeline ---------
__global__ __launch_bounds__(256, 2)
void attn_kernel(const u16* __restrict__ Qh, const u16* __restrict__ Kh,
                 const u16* __restrict__ Vt, u16* __restrict__ attnO) {
  __shared__ __align__(16) u16 lds[3][8192];  // per buf: K[0:4096] V[4096:8192]
  const int tid = threadIdx.x, lane = tid & 63, w = tid >> 6;
  const int bid = blockIdx.x;
  const int x = bid & 7, j = bid >> 3;
  const int half = j >> 5, jj = j & 31;
  const int bh = (x << 2) + (jj >> 4) + (half << 1);  // 4 bh per XCD
  const int r = jj & 15;
  const int qt = half ? r : 15 - r;                    // CU pair sums to 15
  const int h = bh & 15, b = bh >> 4;

  const int qi = lane & 31, hi = lane >> 5;
  const int q0 = (qt << 7) + (w << 5);
  const int qabs = q0 + qi;

  const u16* Qp = Qh + (size_t)(b * 16 + h) * 262144;
  const u16* Kp = Kh + (size_t)(b * 16 + h) * 262144;
  const u16* Vp = Vt + (size_t)((b << 2) + (h >> 2)) * 262144;

  bf16x8 qf[8];
#pragma unroll
  for (int kc = 0; kc < 8; ++kc)
    qf[kc] = *(const bf16x8*)&Qp[(size_t)qabs * 128 + kc * 16 + hi * 8];

  const int kRow = tid >> 4;
  const int kCl = ((tid & 15) ^ (kRow & 7)) << 3;
  const int vRow = tid >> 2;
  const int vCl = ((tid & 3) ^ ((tid >> 3) & 3)) << 3;
  const int ldsoff = tid << 3;

  f32x16 ot[4] = {};
  float mrow = -1e30f, lsum = 0.f;
  const int nt = (qt << 2) + 4;
  const int nt_w = (qt << 2) + w + 1;
  const int swq = qi & 7, swv = (qi >> 1) & 3;

#pragma unroll
  for (int pt = 0; pt < 2; ++pt) {
    u16* bb = (u16*)lds[pt];
    gld_lds16(Kp + (size_t)((pt << 5) + kRow) * 128 + kCl, bb + ldsoff);
    gld_lds16(Kp + (size_t)((pt << 5) + kRow + 16) * 128 + kCl, bb + ldsoff + 2048);
    gld_lds16(Vp + (size_t)vRow * 2048 + (pt << 5) + vCl, bb + 4096 + ldsoff);
    gld_lds16(Vp + (size_t)(vRow + 64) * 2048 + (pt << 5) + vCl, bb + 4096 + ldsoff + 2048);
  }

  int bufc = 0;
  for (int t = 0; t < nt; ++t) {
    asm volatile("s_waitcnt vmcnt(4)" ::: "memory");
    __builtin_amdgcn_sched_barrier(0);
    __builtin_amdgcn_s_barrier();
    {
      const int ts = (t + 2 < nt) ? t + 2 : nt - 1;
      const int bufn = bufc ? bufc - 1 : 2;
      u16* bb = (u16*)lds[bufn];
      gld_lds16(Kp + (size_t)((ts << 5) + kRow) * 128 + kCl, bb + ldsoff);
      gld_lds16(Kp + (size_t)((ts << 5) + kRow + 16) * 128 + kCl, bb + ldsoff + 2048);
      gld_lds16(Vp + (size_t)vRow * 2048 + (ts << 5) + vCl, bb + 4096 + ldsoff);
      gld_lds16(Vp + (size_t)(vRow + 64) * 2048 + (ts << 5) + vCl, bb + 4096 + ldsoff + 2048);
    }
    if (t < nt_w) {
      const u16* kb_ = &lds[bufc][0];
      const u16* vb_ = &lds[bufc][4096];
      f32x16 st = {};
      __builtin_amdgcn_s_setprio(1);
#pragma unroll
      for (int kc = 0; kc < 8; ++kc) {
        bf16x8 kf = *(const bf16x8*)&kb_[(qi << 7) + ((((kc << 1) + hi) ^ swq) << 3)];
        st = mfma32(kf, qf[kc], st);
      }
      __builtin_amdgcn_s_setprio(0);

      if (t == nt_w - 1) {  // diagonal tile
        const int kb0 = t << 5;
#pragma unroll
        for (int reg = 0; reg < 16; ++reg) {
          int kk = kb0 + (reg & 3) + ((reg >> 2) << 3) + (hi << 2);
          if (kk > qabs) st[reg] = -1e30f;
        }
      }

      float tmax = st[0];
#pragma unroll
      for (int reg = 1; reg < 16; ++reg) tmax = fmaxf(tmax, st[reg]);
      tmax = fmaxf(tmax, __shfl_xor(tmax, 32));

      if (__any(tmax - mrow > 11.5f)) {  // defer-max, log2 units
        float nm = fmaxf(mrow, tmax);
        float al = __builtin_amdgcn_exp2f(mrow - nm);
        mrow = nm;
        lsum *= al;
#pragma unroll
        for (int db = 0; db < 4; ++db)
#pragma unroll
          for (int reg = 0; reg < 16; ++reg) ot[db][reg] *= al;
      }

      float psum = 0.f;
#pragma unroll
      for (int reg = 0; reg < 16; ++reg) {
        st[reg] = __builtin_amdgcn_exp2f(st[reg] - mrow);
        psum += st[reg];
      }
      psum += __shfl_xor(psum, 32);
      lsum += psum;

      bf16x8 pfrag[2];
#pragma unroll
      for (int bbp = 0; bbp < 2; ++bbp) {
        unsigned x0 = pk2(st[8 * bbp + 0], st[8 * bbp + 1]);
        unsigned x1 = pk2(st[8 * bbp + 2], st[8 * bbp + 3]);
        unsigned y0 = pk2(st[8 * bbp + 4], st[8 * bbp + 5]);
        unsigned y1 = pk2(st[8 * bbp + 6], st[8 * bbp + 7]);
        asm("v_permlane32_swap_b32 %0, %1" : "+v"(x0), "+v"(y0));
        asm("v_permlane32_swap_b32 %0, %1" : "+v"(x1), "+v"(y1));
        u32x4 uw = { x0, x1, y0, y1 };
        pfrag[bbp] = __builtin_bit_cast(bf16x8, uw);
      }

      __builtin_amdgcn_s_setprio(1);
#pragma unroll
      for (int db = 0; db < 4; ++db) {
        const u16* vr = &vb_[((db << 5) + qi) << 5];
#pragma unroll
        for (int ks = 0; ks < 2; ++ks) {
          bf16x8 vf = *(const bf16x8*)&vr[((((ks << 1) + hi)) ^ swv) << 3];
          ot[db] = mfma32(vf, pfrag[ks], ot[db]);
        }
      }
      __builtin_amdgcn_s_setprio(0);
    }
    bufc = (bufc == 2) ? 0 : bufc + 1;
  }

  float inv = 1.f / lsum;
  u16* rowp = attnO + (size_t)(b * 2048 + qabs) * 2048 + h * 128 + (hi << 2);
#pragma unroll
  for (int db = 0; db < 4; ++db)
#pragma unroll
    for (int mg = 0; mg < 4; ++mg) {
      u16x4 pkv = { f2b(ot[db][4 * mg + 0] * inv), f2b(ot[db][4 * mg + 1] * inv),
                    f2b(ot[db][4 * mg + 2] * inv), f2b(ot[db][4 * mg + 3] * inv) };
      *(u16x4*)&rowp[(db << 5) + (mg << 3)] = pkv;
    }
}

// ---------------------------------------------------------------------------
extern "C" void kernel_launch(void* const* d_in, const int* in_sizes, int n_in,
                              void* d_out, int out_size, void* d_ws, size_t ws_size,
                              hipStream_t stream) {
  const float* x  = (const float*)d_in[0];
  const float* Wq = (const float*)d_in[1];
  const float* Wk = (const float*)d_in[2];
  const float* Wv = (const float*)d_in[3];
  const float* Wo = (const float*)d_in[4];
  float* out = (float*)d_out;
  char* ws = (char*)d_ws;

  u16*      xb   = (u16*)(ws + 0);            // 16 MB
  u16*      wqb  = (u16*)(ws + 16777216);     //  8 MB
  u16*      wkb  = (u16*)(ws + 25165824);     //  2 MB
  u16*      wvb  = (u16*)(ws + 27262976);     //  2 MB
  u16*      wob  = (u16*)(ws + 29360128);     //  8 MB
  unsigned* csT  = (unsigned*)(ws + 37748736);//  8 MB (packed bf16 pairs)
  u16*      Qhp  = (u16*)(ws + 54525952);     // 16 MB
  u16*      Khp  = (u16*)(ws + 71303168);     // 16 MB
  u16*      Vtp  = (u16*)(ws + 88080384);     //  4 MB
  u16*      attnb= (u16*)(ws + 92274688);     // 16 MB

  prep<<<26624, 256, 0, stream>>>((const float4*)x, (const float4*)Wq,
                                  (const float4*)Wk, (const float4*)Wv,
                                  (const float4*)Wo, (u16x4*)xb, (u16x4*)wqb,
                                  (u16x4*)wkb, (u16x4*)wvb, (u16x4*)wob, csT);
  gemm_qkv<<<dim3(12, 16), 512, 0, stream>>>(xb, wqb, wkb, wvb, csT, Qhp, Khp, Vtp);
  attn_kernel<<<512, 256, 0, stream>>>(Qhp, Khp, Vtp, attnb);
  gemm_bt<<<dim3(16, 32), 256, 0, stream>>>(attnb, wob, out, 4096, 2048, 2048);
}

// Round 17
// 197.575 us; speedup vs baseline: 1.0383x; 1.0383x over previous
//
#include <hip/hip_runtime.h>
#include <hip/hip_bf16.h>
#include <stdint.h>

typedef unsigned short u16;
typedef u16 u16x4 __attribute__((ext_vector_type(4)));
typedef unsigned u32x4 __attribute__((ext_vector_type(4)));
typedef __bf16 bf16x8 __attribute__((ext_vector_type(8)));
typedef float f32x4 __attribute__((ext_vector_type(4)));
typedef float f32x16 __attribute__((ext_vector_type(16)));

#define DEVI __device__ __forceinline__

DEVI u16 f2b(float f) {
  __hip_bfloat16 h = __float2bfloat16(f);
  return __builtin_bit_cast(u16, h);
}

DEVI unsigned pk2(float lo, float hi) {
  return (unsigned)f2b(lo) | ((unsigned)f2b(hi) << 16);
}

// unpack packed bf16 pair {lo=cos, hi=sin} -> f32 (no cvt insts needed)
DEVI float unpk_lo(unsigned t) { return __builtin_bit_cast(float, t << 16); }
DEVI float unpk_hi(unsigned t) { return __builtin_bit_cast(float, t & 0xffff0000u); }

DEVI f32x4 mfma16(bf16x8 a, bf16x8 b, f32x4 c) {
  return __builtin_amdgcn_mfma_f32_16x16x32_bf16(a, b, c, 0, 0, 0);
}

DEVI f32x16 mfma32(bf16x8 a, bf16x8 b, f32x16 c) {
  return __builtin_amdgcn_mfma_f32_32x32x16_bf16(a, b, c, 0, 0, 0);
}

DEVI void gld_lds16(const u16* g, u16* l) {
  __builtin_amdgcn_global_load_lds(
      (const __attribute__((address_space(1))) unsigned int*)g,
      (__attribute__((address_space(3))) unsigned int*)l, 16, 0, 0);
}

// ---------------- prep: rope table (blocks 0..8191) + cvt (8192..26623) ----
// table packed: u32 = {cos bf16, sin bf16} -> half the table traffic.
__global__ void prep(const float4* __restrict__ x, const float4* __restrict__ wq,
                     const float4* __restrict__ wk, const float4* __restrict__ wv,
                     const float4* __restrict__ wo,
                     u16x4* __restrict__ xb, u16x4* __restrict__ wqb,
                     u16x4* __restrict__ wkb, u16x4* __restrict__ wvb,
                     u16x4* __restrict__ wob, unsigned* __restrict__ csT) {
  long bid = blockIdx.x;
  if (bid < 8192) {
    int i = (int)bid * 256 + threadIdx.x;
    int s = i >> 10, p = i & 1023;
    float freq = exp2f((float)p * -0.012976281620653759f);
    float ang = (float)s * freq;
    float sv, cv;
    __sincosf(ang, &sv, &cv);
    csT[i] = pk2(cv, sv);
    return;
  }
  long i = (bid - 8192) * 256 + threadIdx.x;
  const float4* src; u16x4* dst; long o;
  if (i < 2097152)      { src = x;  dst = xb;  o = i; }
  else if (i < 3145728) { src = wq; dst = wqb; o = i - 2097152; }
  else if (i < 3407872) { src = wk; dst = wkb; o = i - 3145728; }
  else if (i < 3670016) { src = wv; dst = wvb; o = i - 3407872; }
  else                  { src = wo; dst = wob; o = i - 3670016; }
  float4 v = src[o];
  u16x4 r = { f2b(v.x), f2b(v.y), f2b(v.z), f2b(v.w) };
  dst[o] = r;
}

// ---------------- fused QKV GEMM: 256x256 tile, 512 thr, 3-buf vmcnt -------
// (R15-proven verbatim: best measured qkv config, 75.9 us)
__global__ __launch_bounds__(512)
void gemm_qkv(const u16* __restrict__ A, const u16* __restrict__ wq,
              const u16* __restrict__ wk, const u16* __restrict__ wv,
              const unsigned* __restrict__ csT, u16* __restrict__ Qh,
              u16* __restrict__ Kh, u16* __restrict__ Vtp) {
  __shared__ __align__(16) u16 lds[3][16384];  // per buf: A[0:8192] B[8192:16384]
  const int tid = threadIdx.x;
  const int lane = tid & 63;
  const int w = tid >> 6;               // 0..7
  const int wr = w >> 2, wc = w & 3;    // 2 x 4 waves
  const int x = blockIdx.x, m0 = blockIdx.y << 8, n0 = x << 8;
  const int K = 2048;

  const u16* Bw;
  int mode;
  if (x < 8)       { Bw = wq + (size_t)n0 * K;          mode = 0; }
  else if (x < 10) { Bw = wk + (size_t)(n0 - 2048) * K; mode = 1; }
  else             { Bw = wv + (size_t)(n0 - 2560) * K; mode = 2; }

  const int srow = tid >> 2;            // 0..127
  const int cs = (tid & 3) ^ ((srow >> 1) & 3);
  const int p = srow & 63, p4 = p >> 4, pl = p & 15;
  const int prow = (srow & ~63) | (pl << 1) | (p4 & 1) | ((p4 & 2) << 4);
  const int bsrc = (mode == 2) ? srow : prow;
  const u16* ga0 = A + (size_t)(m0 + srow) * K + (cs << 3);
  const u16* gb0 = Bw + (size_t)bsrc * K + (cs << 3);
  const size_t rstep = (size_t)128 * K;

  f32x4 acc[8][4] = {};
  const int nk = K >> 5;

#define QKV_STAGE(buf, ks)                                        \
  {                                                               \
    u16* l0 = &lds[buf][tid << 3];                                \
    const u16* ga_ = ga0 + ((size_t)(ks) << 5);                   \
    const u16* gb_ = gb0 + ((size_t)(ks) << 5);                   \
    gld_lds16(ga_, l0);                                           \
    gld_lds16(ga_ + rstep, l0 + 4096);                            \
    gld_lds16(gb_, l0 + 8192);                                    \
    gld_lds16(gb_ + rstep, l0 + 12288);                           \
  }

  QKV_STAGE(0, 0);
  QKV_STAGE(1, 1);

  const int l15 = lane & 15;
  const int lg = lane >> 4;
  const int ch8 = (lg ^ ((l15 >> 1) & 3)) << 3;
  const int arow0 = (wr << 7) + l15;    // + mi*16
  const int brow0 = (wc << 6) + l15;    // + ni*16

  int bufc = 0;
  for (int kt = 0; kt < nk; ++kt) {
    asm volatile("s_waitcnt vmcnt(4)" ::: "memory");
    __builtin_amdgcn_sched_barrier(0);
    __builtin_amdgcn_s_barrier();
    {
      const int ts = (kt + 2 < nk) ? kt + 2 : nk - 1;
      const int bufn = bufc ? bufc - 1 : 2;
      QKV_STAGE(bufn, ts);
    }
    const u16* la = &lds[bufc][0];
    const u16* lb = &lds[bufc][8192];
    bf16x8 af[8], bfr[4];
#pragma unroll
    for (int mi = 0; mi < 8; ++mi)
      af[mi] = *(const bf16x8*)&la[((arow0 + (mi << 4)) << 5) + ch8];
#pragma unroll
    for (int ni = 0; ni < 4; ++ni)
      bfr[ni] = *(const bf16x8*)&lb[((brow0 + (ni << 4)) << 5) + ch8];
    __builtin_amdgcn_s_setprio(1);
#pragma unroll
    for (int mi = 0; mi < 8; ++mi)
#pragma unroll
      for (int ni = 0; ni < 4; ++ni)
        acc[mi][ni] = mfma16(af[mi], bfr[ni], acc[mi][ni]);
    __builtin_amdgcn_s_setprio(0);
    bufc = (bufc == 2) ? 0 : bufc + 1;
  }
  asm volatile("s_waitcnt vmcnt(0)" ::: "memory");
#undef QKV_STAGE

  const int crow = (lane >> 4) << 2;
  if (mode == 0) {
    const float SCL = 0.022097086912079608f * 1.4426950408889634f;  // /sqrt(2048)*log2e
    const int h = (x << 1) + (wc >> 1);
    const int hd0 = ((wc & 1) << 6) + (l15 << 1);
    const int tb = (h << 6) + ((wc & 1) << 5) + l15;
#pragma unroll
    for (int mi = 0; mi < 8; ++mi)
#pragma unroll
      for (int rr = 0; rr < 4; ++rr) {
        int row = m0 + (wr << 7) + (mi << 4) + crow + rr;
        int s = row & 2047, b = row >> 11;
        unsigned tA = csT[(s << 10) + tb];
        unsigned tB = csT[(s << 10) + tb + 16];
        float cAc = unpk_lo(tA), cAs = unpk_hi(tA);
        float cBc = unpk_lo(tB), cBs = unpk_hi(tB);
        float v0 = acc[mi][0][rr], v1 = acc[mi][1][rr];
        float v2 = acc[mi][2][rr], v3 = acc[mi][3][rr];
        unsigned lo = pk2((v0 * cAc - v1 * cAs) * SCL, (v0 * cAs + v1 * cAc) * SCL);
        unsigned hi = pk2((v2 * cBc - v3 * cBs) * SCL, (v2 * cBs + v3 * cBc) * SCL);
        u16* dst = &Qh[((size_t)(b * 16 + h) * 2048 + s) * 128 + hd0];
        *(unsigned*)dst = lo;
        *(unsigned*)(dst + 32) = hi;
      }
  } else if (mode == 1) {
    const int kvh = ((x - 8) << 1) + (wc >> 1);
    const int hd0 = ((wc & 1) << 6) + (l15 << 1);
#pragma unroll
    for (int mi = 0; mi < 8; ++mi)
#pragma unroll
      for (int rr = 0; rr < 4; ++rr) {
        int row = m0 + (wr << 7) + (mi << 4) + crow + rr;
        int s = row & 2047, b = row >> 11;
        float v0 = acc[mi][0][rr], v1 = acc[mi][1][rr];
        float v2 = acc[mi][2][rr], v3 = acc[mi][3][rr];
#pragma unroll
        for (int g = 0; g < 4; ++g) {
          int h = (kvh << 2) + g;
          int tb = (h << 6) + ((wc & 1) << 5) + l15;
          unsigned tA = csT[(s << 10) + tb];
          unsigned tB = csT[(s << 10) + tb + 16];
          float cAc = unpk_lo(tA), cAs = unpk_hi(tA);
          float cBc = unpk_lo(tB), cBs = unpk_hi(tB);
          unsigned lo = pk2(v0 * cAc - v1 * cAs, v0 * cAs + v1 * cAc);
          unsigned hi = pk2(v2 * cBc - v3 * cBs, v2 * cBs + v3 * cBc);
          u16* dst = &Kh[((size_t)(b * 16 + h) * 2048 + s) * 128 + hd0];
          *(unsigned*)dst = lo;
          *(unsigned*)(dst + 32) = hi;
        }
      }
  } else {
#pragma unroll
    for (int mi = 0; mi < 8; ++mi) {
      int sg = m0 + (wr << 7) + (mi << 4) + crow;
      int b = sg >> 11, s = sg & 2047;
#pragma unroll
      for (int ni = 0; ni < 4; ++ni) {
        int n = ((x - 10) << 8) + (wc << 6) + (ni << 4) + l15;
        u16x4 pk = { f2b(acc[mi][ni][0]), f2b(acc[mi][ni][1]),
                     f2b(acc[mi][ni][2]), f2b(acc[mi][ni][3]) };
        *(u16x4*)&Vtp[((size_t)((b << 2) + (n >> 7)) * 128 + (n & 127)) * 2048 + s] = pk;
      }
    }
  }
}

// ---------------- O-projection GEMM: 128x128, 2-buf sync, swizzled, 512 blk
__global__ __launch_bounds__(256)
void gemm_bt(const u16* __restrict__ A, const u16* __restrict__ Bw,
             float* __restrict__ C, int M, int N, int K) {
  __shared__ __align__(16) u16 lds[2][2][4096];
  const int tid = threadIdx.x;
  const int lane = tid & 63;
  const int w = tid >> 6;
  const int wr = w >> 1, wc = w & 1;
  const int m0 = blockIdx.y << 7, n0 = blockIdx.x << 7;

  const int srow = tid >> 2;
  const int cs = (tid & 3) ^ ((srow >> 1) & 3);
  const u16* ga0 = A + (size_t)(m0 + srow) * K + (cs << 3);
  const u16* gb0 = Bw + (size_t)(n0 + srow) * K + (cs << 3);
  const size_t rstep = (size_t)64 * K;

  f32x4 acc[4][4] = {};
  const int nk = K >> 5;
  int cur = 0;

  {
    u16* la = &lds[0][0][tid << 3];
    u16* lb = &lds[0][1][tid << 3];
    gld_lds16(ga0, la);
    gld_lds16(ga0 + rstep, la + 2048);
    gld_lds16(gb0, lb);
    gld_lds16(gb0 + rstep, lb + 2048);
  }
  __syncthreads();

  const int l15 = lane & 15;
  const int lg = lane >> 4;
  const int ch8 = (lg ^ ((l15 >> 1) & 3)) << 3;
  const int abase = (((wr << 6) + l15) << 5) + ch8;
  const int bbase = (((wc << 6) + l15) << 5) + ch8;

  for (int kt = 0; kt < nk; ++kt) {
    if (kt + 1 < nk) {
      const u16* ga = ga0 + ((size_t)(kt + 1) << 5);
      const u16* gb = gb0 + ((size_t)(kt + 1) << 5);
      u16* la = &lds[cur ^ 1][0][tid << 3];
      u16* lb = &lds[cur ^ 1][1][tid << 3];
      gld_lds16(ga, la);
      gld_lds16(ga + rstep, la + 2048);
      gld_lds16(gb, lb);
      gld_lds16(gb + rstep, lb + 2048);
    }
    const u16* la = &lds[cur][0][0];
    const u16* lb = &lds[cur][1][0];
    bf16x8 af[4], bfr[4];
#pragma unroll
    for (int mi = 0; mi < 4; ++mi)
      af[mi] = *(const bf16x8*)&la[abase + (mi << 9)];
#pragma unroll
    for (int ni = 0; ni < 4; ++ni)
      bfr[ni] = *(const bf16x8*)&lb[bbase + (ni << 9)];
#pragma unroll
    for (int mi = 0; mi < 4; ++mi)
#pragma unroll
      for (int ni = 0; ni < 4; ++ni)
        acc[mi][ni] = mfma16(af[mi], bfr[ni], acc[mi][ni]);
    __syncthreads();
    cur ^= 1;
  }

  const int crow = (lane >> 4) << 2;
#pragma unroll
  for (int mi = 0; mi < 4; ++mi) {
    int row = m0 + (wr << 6) + (mi << 4) + crow;
#pragma unroll
    for (int ni = 0; ni < 4; ++ni) {
      int col = n0 + (wc << 6) + (ni << 4) + l15;
#pragma unroll
      for (int rr = 0; rr < 4; ++rr)
        C[(size_t)(row + rr) * N + col] = acc[mi][ni][rr];
    }
  }
}

// ---------------- flash attention: counted-vmcnt 3-buffer pipeline ---------
__global__ __launch_bounds__(256, 2)
void attn_kernel(const u16* __restrict__ Qh, const u16* __restrict__ Kh,
                 const u16* __restrict__ Vt, u16* __restrict__ attnO) {
  __shared__ __align__(16) u16 lds[3][8192];  // per buf: K[0:4096] V[4096:8192]
  const int tid = threadIdx.x, lane = tid & 63, w = tid >> 6;
  const int bid = blockIdx.x;
  const int x = bid & 7, j = bid >> 3;
  const int half = j >> 5, jj = j & 31;
  const int bh = (x << 2) + (jj >> 4) + (half << 1);  // 4 bh per XCD
  const int r = jj & 15;
  const int qt = half ? r : 15 - r;                    // CU pair sums to 15
  const int h = bh & 15, b = bh >> 4;

  const int qi = lane & 31, hi = lane >> 5;
  const int q0 = (qt << 7) + (w << 5);
  const int qabs = q0 + qi;

  const u16* Qp = Qh + (size_t)(b * 16 + h) * 262144;
  const u16* Kp = Kh + (size_t)(b * 16 + h) * 262144;
  const u16* Vp = Vt + (size_t)((b << 2) + (h >> 2)) * 262144;

  bf16x8 qf[8];
#pragma unroll
  for (int kc = 0; kc < 8; ++kc)
    qf[kc] = *(const bf16x8*)&Qp[(size_t)qabs * 128 + kc * 16 + hi * 8];

  const int kRow = tid >> 4;
  const int kCl = ((tid & 15) ^ (kRow & 7)) << 3;
  const int vRow = tid >> 2;
  const int vCl = ((tid & 3) ^ ((tid >> 3) & 3)) << 3;
  const int ldsoff = tid << 3;

  f32x16 ot[4] = {};
  float mrow = -1e30f, lsum = 0.f;
  const int nt = (qt << 2) + 4;
  const int nt_w = (qt << 2) + w + 1;
  const int swq = qi & 7, swv = (qi >> 1) & 3;

#pragma unroll
  for (int pt = 0; pt < 2; ++pt) {
    u16* bb = (u16*)lds[pt];
    gld_lds16(Kp + (size_t)((pt << 5) + kRow) * 128 + kCl, bb + ldsoff);
    gld_lds16(Kp + (size_t)((pt << 5) + kRow + 16) * 128 + kCl, bb + ldsoff + 2048);
    gld_lds16(Vp + (size_t)vRow * 2048 + (pt << 5) + vCl, bb + 4096 + ldsoff);
    gld_lds16(Vp + (size_t)(vRow + 64) * 2048 + (pt << 5) + vCl, bb + 4096 + ldsoff + 2048);
  }

  int bufc = 0;
  for (int t = 0; t < nt; ++t) {
    asm volatile("s_waitcnt vmcnt(4)" ::: "memory");
    __builtin_amdgcn_sched_barrier(0);
    __builtin_amdgcn_s_barrier();
    {
      const int ts = (t + 2 < nt) ? t + 2 : nt - 1;
      const int bufn = bufc ? bufc - 1 : 2;
      u16* bb = (u16*)lds[bufn];
      gld_lds16(Kp + (size_t)((ts << 5) + kRow) * 128 + kCl, bb + ldsoff);
      gld_lds16(Kp + (size_t)((ts << 5) + kRow + 16) * 128 + kCl, bb + ldsoff + 2048);
      gld_lds16(Vp + (size_t)vRow * 2048 + (ts << 5) + vCl, bb + 4096 + ldsoff);
      gld_lds16(Vp + (size_t)(vRow + 64) * 2048 + (ts << 5) + vCl, bb + 4096 + ldsoff + 2048);
    }
    if (t < nt_w) {
      const u16* kb_ = &lds[bufc][0];
      const u16* vb_ = &lds[bufc][4096];
      f32x16 st = {};
      __builtin_amdgcn_s_setprio(1);
#pragma unroll
      for (int kc = 0; kc < 8; ++kc) {
        bf16x8 kf = *(const bf16x8*)&kb_[(qi << 7) + ((((kc << 1) + hi) ^ swq) << 3)];
        st = mfma32(kf, qf[kc], st);
      }
      __builtin_amdgcn_s_setprio(0);

      if (t == nt_w - 1) {  // diagonal tile
        const int kb0 = t << 5;
#pragma unroll
        for (int reg = 0; reg < 16; ++reg) {
          int kk = kb0 + (reg & 3) + ((reg >> 2) << 3) + (hi << 2);
          if (kk > qabs) st[reg] = -1e30f;
        }
      }

      float tmax = st[0];
#pragma unroll
      for (int reg = 1; reg < 16; ++reg) tmax = fmaxf(tmax, st[reg]);
      tmax = fmaxf(tmax, __shfl_xor(tmax, 32));

      if (__any(tmax - mrow > 11.5f)) {  // defer-max, log2 units
        float nm = fmaxf(mrow, tmax);
        float al = __builtin_amdgcn_exp2f(mrow - nm);
        mrow = nm;
        lsum *= al;
#pragma unroll
        for (int db = 0; db < 4; ++db)
#pragma unroll
          for (int reg = 0; reg < 16; ++reg) ot[db][reg] *= al;
      }

      float psum = 0.f;
#pragma unroll
      for (int reg = 0; reg < 16; ++reg) {
        st[reg] = __builtin_amdgcn_exp2f(st[reg] - mrow);
        psum += st[reg];
      }
      psum += __shfl_xor(psum, 32);
      lsum += psum;

      bf16x8 pfrag[2];
#pragma unroll
      for (int bbp = 0; bbp < 2; ++bbp) {
        unsigned x0 = pk2(st[8 * bbp + 0], st[8 * bbp + 1]);
        unsigned x1 = pk2(st[8 * bbp + 2], st[8 * bbp + 3]);
        unsigned y0 = pk2(st[8 * bbp + 4], st[8 * bbp + 5]);
        unsigned y1 = pk2(st[8 * bbp + 6], st[8 * bbp + 7]);
        asm("v_permlane32_swap_b32 %0, %1" : "+v"(x0), "+v"(y0));
        asm("v_permlane32_swap_b32 %0, %1" : "+v"(x1), "+v"(y1));
        u32x4 uw = { x0, x1, y0, y1 };
        pfrag[bbp] = __builtin_bit_cast(bf16x8, uw);
      }

      __builtin_amdgcn_s_setprio(1);
#pragma unroll
      for (int db = 0; db < 4; ++db) {
        const u16* vr = &vb_[((db << 5) + qi) << 5];
#pragma unroll
        for (int ks = 0; ks < 2; ++ks) {
          bf16x8 vf = *(const bf16x8*)&vr[((((ks << 1) + hi)) ^ swv) << 3];
          ot[db] = mfma32(vf, pfrag[ks], ot[db]);
        }
      }
      __builtin_amdgcn_s_setprio(0);
    }
    bufc = (bufc == 2) ? 0 : bufc + 1;
  }

  float inv = 1.f / lsum;
  u16* rowp = attnO + (size_t)(b * 2048 + qabs) * 2048 + h * 128 + (hi << 2);
#pragma unroll
  for (int db = 0; db < 4; ++db)
#pragma unroll
    for (int mg = 0; mg < 4; ++mg) {
      u16x4 pkv = { f2b(ot[db][4 * mg + 0] * inv), f2b(ot[db][4 * mg + 1] * inv),
                    f2b(ot[db][4 * mg + 2] * inv), f2b(ot[db][4 * mg + 3] * inv) };
      *(u16x4*)&rowp[(db << 5) + (mg << 3)] = pkv;
    }
}

// ---------------------------------------------------------------------------
extern "C" void kernel_launch(void* const* d_in, const int* in_sizes, int n_in,
                              void* d_out, int out_size, void* d_ws, size_t ws_size,
                              hipStream_t stream) {
  const float* x  = (const float*)d_in[0];
  const float* Wq = (const float*)d_in[1];
  const float* Wk = (const float*)d_in[2];
  const float* Wv = (const float*)d_in[3];
  const float* Wo = (const float*)d_in[4];
  float* out = (float*)d_out;
  char* ws = (char*)d_ws;

  u16*      xb   = (u16*)(ws + 0);            // 16 MB
  u16*      wqb  = (u16*)(ws + 16777216);     //  8 MB
  u16*      wkb  = (u16*)(ws + 25165824);     //  2 MB
  u16*      wvb  = (u16*)(ws + 27262976);     //  2 MB
  u16*      wob  = (u16*)(ws + 29360128);     //  8 MB
  unsigned* csT  = (unsigned*)(ws + 37748736);//  8 MB (packed bf16 pairs)
  u16*      Qhp  = (u16*)(ws + 54525952);     // 16 MB
  u16*      Khp  = (u16*)(ws + 71303168);     // 16 MB
  u16*      Vtp  = (u16*)(ws + 88080384);     //  4 MB
  u16*      attnb= (u16*)(ws + 92274688);     // 16 MB

  prep<<<26624, 256, 0, stream>>>((const float4*)x, (const float4*)Wq,
                                  (const float4*)Wk, (const float4*)Wv,
                                  (const float4*)Wo, (u16x4*)xb, (u16x4*)wqb,
                                  (u16x4*)wkb, (u16x4*)wvb, (u16x4*)wob, csT);
  gemm_qkv<<<dim3(12, 16), 512, 0, stream>>>(xb, wqb, wkb, wvb, csT, Qhp, Khp, Vtp);
  attn_kernel<<<512, 256, 0, stream>>>(Qhp, Khp, Vtp, attnb);
  gemm_bt<<<dim3(16, 32), 256, 0, stream>>>(attnb, wob, out, 4096, 2048, 2048);
}

// Round 18
// 196.944 us; speedup vs baseline: 1.0416x; 1.0032x over previous
//
#include <hip/hip_runtime.h>
#include <hip/hip_bf16.h>
#include <stdint.h>

typedef unsigned short u16;
typedef u16 u16x4 __attribute__((ext_vector_type(4)));
typedef unsigned u32x4 __attribute__((ext_vector_type(4)));
typedef __bf16 bf16x8 __attribute__((ext_vector_type(8)));
typedef float f32x4 __attribute__((ext_vector_type(4)));
typedef float f32x16 __attribute__((ext_vector_type(16)));

#define DEVI __device__ __forceinline__

DEVI u16 f2b(float f) {
  __hip_bfloat16 h = __float2bfloat16(f);
  return __builtin_bit_cast(u16, h);
}

DEVI unsigned pk2(float lo, float hi) {
  return (unsigned)f2b(lo) | ((unsigned)f2b(hi) << 16);
}

// unpack packed bf16 pair {lo=cos, hi=sin} -> f32 (no cvt insts needed)
DEVI float unpk_lo(unsigned t) { return __builtin_bit_cast(float, t << 16); }
DEVI float unpk_hi(unsigned t) { return __builtin_bit_cast(float, t & 0xffff0000u); }

DEVI f32x4 mfma16(bf16x8 a, bf16x8 b, f32x4 c) {
  return __builtin_amdgcn_mfma_f32_16x16x32_bf16(a, b, c, 0, 0, 0);
}

DEVI f32x16 mfma32(bf16x8 a, bf16x8 b, f32x16 c) {
  return __builtin_amdgcn_mfma_f32_32x32x16_bf16(a, b, c, 0, 0, 0);
}

DEVI void gld_lds16(const u16* g, u16* l) {
  __builtin_amdgcn_global_load_lds(
      (const __attribute__((address_space(1))) unsigned int*)g,
      (__attribute__((address_space(3))) unsigned int*)l, 16, 0, 0);
}

// ---------------- prep: rope table (blocks 0..8191) + cvt (8192..26623) ----
// table packed: u32 = {cos bf16, sin bf16} -> half the table traffic.
__global__ void prep(const float4* __restrict__ x, const float4* __restrict__ wq,
                     const float4* __restrict__ wk, const float4* __restrict__ wv,
                     const float4* __restrict__ wo,
                     u16x4* __restrict__ xb, u16x4* __restrict__ wqb,
                     u16x4* __restrict__ wkb, u16x4* __restrict__ wvb,
                     u16x4* __restrict__ wob, unsigned* __restrict__ csT) {
  long bid = blockIdx.x;
  if (bid < 8192) {
    int i = (int)bid * 256 + threadIdx.x;
    int s = i >> 10, p = i & 1023;
    float freq = exp2f((float)p * -0.012976281620653759f);
    float ang = (float)s * freq;
    float sv, cv;
    __sincosf(ang, &sv, &cv);
    csT[i] = pk2(cv, sv);
    return;
  }
  long i = (bid - 8192) * 256 + threadIdx.x;
  const float4* src; u16x4* dst; long o;
  if (i < 2097152)      { src = x;  dst = xb;  o = i; }
  else if (i < 3145728) { src = wq; dst = wqb; o = i - 2097152; }
  else if (i < 3407872) { src = wk; dst = wkb; o = i - 3145728; }
  else if (i < 3670016) { src = wv; dst = wvb; o = i - 3407872; }
  else                  { src = wo; dst = wob; o = i - 3670016; }
  float4 v = src[o];
  u16x4 r = { f2b(v.x), f2b(v.y), f2b(v.z), f2b(v.w) };
  dst[o] = r;
}

// ---------------- fused QKV GEMM: 256x256 tile, 512 thr, 3-buf vmcnt -------
// (session-best proven config: 75.9-76.6 us, MfmaUtil ~26%, 0 conflicts)
__global__ __launch_bounds__(512)
void gemm_qkv(const u16* __restrict__ A, const u16* __restrict__ wq,
              const u16* __restrict__ wk, const u16* __restrict__ wv,
              const unsigned* __restrict__ csT, u16* __restrict__ Qh,
              u16* __restrict__ Kh, u16* __restrict__ Vtp) {
  __shared__ __align__(16) u16 lds[3][16384];  // per buf: A[0:8192] B[8192:16384]
  const int tid = threadIdx.x;
  const int lane = tid & 63;
  const int w = tid >> 6;               // 0..7
  const int wr = w >> 2, wc = w & 3;    // 2 x 4 waves
  const int x = blockIdx.x, m0 = blockIdx.y << 8, n0 = x << 8;
  const int K = 2048;

  const u16* Bw;
  int mode;
  if (x < 8)       { Bw = wq + (size_t)n0 * K;          mode = 0; }
  else if (x < 10) { Bw = wk + (size_t)(n0 - 2048) * K; mode = 1; }
  else             { Bw = wv + (size_t)(n0 - 2560) * K; mode = 2; }

  const int srow = tid >> 2;            // 0..127
  const int cs = (tid & 3) ^ ((srow >> 1) & 3);
  const int p = srow & 63, p4 = p >> 4, pl = p & 15;
  const int prow = (srow & ~63) | (pl << 1) | (p4 & 1) | ((p4 & 2) << 4);
  const int bsrc = (mode == 2) ? srow : prow;
  const u16* ga0 = A + (size_t)(m0 + srow) * K + (cs << 3);
  const u16* gb0 = Bw + (size_t)bsrc * K + (cs << 3);
  const size_t rstep = (size_t)128 * K;

  f32x4 acc[8][4] = {};
  const int nk = K >> 5;

#define QKV_STAGE(buf, ks)                                        \
  {                                                               \
    u16* l0 = &lds[buf][tid << 3];                                \
    const u16* ga_ = ga0 + ((size_t)(ks) << 5);                   \
    const u16* gb_ = gb0 + ((size_t)(ks) << 5);                   \
    gld_lds16(ga_, l0);                                           \
    gld_lds16(ga_ + rstep, l0 + 4096);                            \
    gld_lds16(gb_, l0 + 8192);                                    \
    gld_lds16(gb_ + rstep, l0 + 12288);                           \
  }

  QKV_STAGE(0, 0);
  QKV_STAGE(1, 1);

  const int l15 = lane & 15;
  const int lg = lane >> 4;
  const int ch8 = (lg ^ ((l15 >> 1) & 3)) << 3;
  const int arow0 = (wr << 7) + l15;    // + mi*16
  const int brow0 = (wc << 6) + l15;    // + ni*16

  int bufc = 0;
  for (int kt = 0; kt < nk; ++kt) {
    asm volatile("s_waitcnt vmcnt(4)" ::: "memory");
    __builtin_amdgcn_sched_barrier(0);
    __builtin_amdgcn_s_barrier();
    {
      const int ts = (kt + 2 < nk) ? kt + 2 : nk - 1;
      const int bufn = bufc ? bufc - 1 : 2;
      QKV_STAGE(bufn, ts);
    }
    const u16* la = &lds[bufc][0];
    const u16* lb = &lds[bufc][8192];
    bf16x8 af[8], bfr[4];
#pragma unroll
    for (int mi = 0; mi < 8; ++mi)
      af[mi] = *(const bf16x8*)&la[((arow0 + (mi << 4)) << 5) + ch8];
#pragma unroll
    for (int ni = 0; ni < 4; ++ni)
      bfr[ni] = *(const bf16x8*)&lb[((brow0 + (ni << 4)) << 5) + ch8];
    __builtin_amdgcn_s_setprio(1);
#pragma unroll
    for (int mi = 0; mi < 8; ++mi)
#pragma unroll
      for (int ni = 0; ni < 4; ++ni)
        acc[mi][ni] = mfma16(af[mi], bfr[ni], acc[mi][ni]);
    __builtin_amdgcn_s_setprio(0);
    bufc = (bufc == 2) ? 0 : bufc + 1;
  }
  asm volatile("s_waitcnt vmcnt(0)" ::: "memory");
#undef QKV_STAGE

  const int crow = (lane >> 4) << 2;
  if (mode == 0) {
    const float SCL = 0.022097086912079608f * 1.4426950408889634f;  // /sqrt(2048)*log2e
    const int h = (x << 1) + (wc >> 1);
    const int hd0 = ((wc & 1) << 6) + (l15 << 1);
    const int tb = (h << 6) + ((wc & 1) << 5) + l15;
#pragma unroll
    for (int mi = 0; mi < 8; ++mi)
#pragma unroll
      for (int rr = 0; rr < 4; ++rr) {
        int row = m0 + (wr << 7) + (mi << 4) + crow + rr;
        int s = row & 2047, b = row >> 11;
        unsigned tA = csT[(s << 10) + tb];
        unsigned tB = csT[(s << 10) + tb + 16];
        float cAc = unpk_lo(tA), cAs = unpk_hi(tA);
        float cBc = unpk_lo(tB), cBs = unpk_hi(tB);
        float v0 = acc[mi][0][rr], v1 = acc[mi][1][rr];
        float v2 = acc[mi][2][rr], v3 = acc[mi][3][rr];
        unsigned lo = pk2((v0 * cAc - v1 * cAs) * SCL, (v0 * cAs + v1 * cAc) * SCL);
        unsigned hi = pk2((v2 * cBc - v3 * cBs) * SCL, (v2 * cBs + v3 * cBc) * SCL);
        u16* dst = &Qh[((size_t)(b * 16 + h) * 2048 + s) * 128 + hd0];
        *(unsigned*)dst = lo;
        *(unsigned*)(dst + 32) = hi;
      }
  } else if (mode == 1) {
    const int kvh = ((x - 8) << 1) + (wc >> 1);
    const int hd0 = ((wc & 1) << 6) + (l15 << 1);
#pragma unroll
    for (int mi = 0; mi < 8; ++mi)
#pragma unroll
      for (int rr = 0; rr < 4; ++rr) {
        int row = m0 + (wr << 7) + (mi << 4) + crow + rr;
        int s = row & 2047, b = row >> 11;
        float v0 = acc[mi][0][rr], v1 = acc[mi][1][rr];
        float v2 = acc[mi][2][rr], v3 = acc[mi][3][rr];
#pragma unroll
        for (int g = 0; g < 4; ++g) {
          int h = (kvh << 2) + g;
          int tb = (h << 6) + ((wc & 1) << 5) + l15;
          unsigned tA = csT[(s << 10) + tb];
          unsigned tB = csT[(s << 10) + tb + 16];
          float cAc = unpk_lo(tA), cAs = unpk_hi(tA);
          float cBc = unpk_lo(tB), cBs = unpk_hi(tB);
          unsigned lo = pk2(v0 * cAc - v1 * cAs, v0 * cAs + v1 * cAc);
          unsigned hi = pk2(v2 * cBc - v3 * cBs, v2 * cBs + v3 * cBc);
          u16* dst = &Kh[((size_t)(b * 16 + h) * 2048 + s) * 128 + hd0];
          *(unsigned*)dst = lo;
          *(unsigned*)(dst + 32) = hi;
        }
      }
  } else {
#pragma unroll
    for (int mi = 0; mi < 8; ++mi) {
      int sg = m0 + (wr << 7) + (mi << 4) + crow;
      int b = sg >> 11, s = sg & 2047;
#pragma unroll
      for (int ni = 0; ni < 4; ++ni) {
        int n = ((x - 10) << 8) + (wc << 6) + (ni << 4) + l15;
        u16x4 pk = { f2b(acc[mi][ni][0]), f2b(acc[mi][ni][1]),
                     f2b(acc[mi][ni][2]), f2b(acc[mi][ni][3]) };
        *(u16x4*)&Vtp[((size_t)((b << 2) + (n >> 7)) * 128 + (n & 127)) * 2048 + s] = pk;
      }
    }
  }
}

// ---------------- O-projection GEMM: 128x128, 2-buf sync, swizzled, 512 blk
__global__ __launch_bounds__(256)
void gemm_bt(const u16* __restrict__ A, const u16* __restrict__ Bw,
             float* __restrict__ C, int M, int N, int K) {
  __shared__ __align__(16) u16 lds[2][2][4096];
  const int tid = threadIdx.x;
  const int lane = tid & 63;
  const int w = tid >> 6;
  const int wr = w >> 1, wc = w & 1;
  const int m0 = blockIdx.y << 7, n0 = blockIdx.x << 7;

  const int srow = tid >> 2;
  const int cs = (tid & 3) ^ ((srow >> 1) & 3);
  const u16* ga0 = A + (size_t)(m0 + srow) * K + (cs << 3);
  const u16* gb0 = Bw + (size_t)(n0 + srow) * K + (cs << 3);
  const size_t rstep = (size_t)64 * K;

  f32x4 acc[4][4] = {};
  const int nk = K >> 5;
  int cur = 0;

  {
    u16* la = &lds[0][0][tid << 3];
    u16* lb = &lds[0][1][tid << 3];
    gld_lds16(ga0, la);
    gld_lds16(ga0 + rstep, la + 2048);
    gld_lds16(gb0, lb);
    gld_lds16(gb0 + rstep, lb + 2048);
  }
  __syncthreads();

  const int l15 = lane & 15;
  const int lg = lane >> 4;
  const int ch8 = (lg ^ ((l15 >> 1) & 3)) << 3;
  const int abase = (((wr << 6) + l15) << 5) + ch8;
  const int bbase = (((wc << 6) + l15) << 5) + ch8;

  for (int kt = 0; kt < nk; ++kt) {
    if (kt + 1 < nk) {
      const u16* ga = ga0 + ((size_t)(kt + 1) << 5);
      const u16* gb = gb0 + ((size_t)(kt + 1) << 5);
      u16* la = &lds[cur ^ 1][0][tid << 3];
      u16* lb = &lds[cur ^ 1][1][tid << 3];
      gld_lds16(ga, la);
      gld_lds16(ga + rstep, la + 2048);
      gld_lds16(gb, lb);
      gld_lds16(gb + rstep, lb + 2048);
    }
    const u16* la = &lds[cur][0][0];
    const u16* lb = &lds[cur][1][0];
    bf16x8 af[4], bfr[4];
#pragma unroll
    for (int mi = 0; mi < 4; ++mi)
      af[mi] = *(const bf16x8*)&la[abase + (mi << 9)];
#pragma unroll
    for (int ni = 0; ni < 4; ++ni)
      bfr[ni] = *(const bf16x8*)&lb[bbase + (ni << 9)];
#pragma unroll
    for (int mi = 0; mi < 4; ++mi)
#pragma unroll
      for (int ni = 0; ni < 4; ++ni)
        acc[mi][ni] = mfma16(af[mi], bfr[ni], acc[mi][ni]);
    __syncthreads();
    cur ^= 1;
  }

  const int crow = (lane >> 4) << 2;
#pragma unroll
  for (int mi = 0; mi < 4; ++mi) {
    int row = m0 + (wr << 6) + (mi << 4) + crow;
#pragma unroll
    for (int ni = 0; ni < 4; ++ni) {
      int col = n0 + (wc << 6) + (ni << 4) + l15;
#pragma unroll
      for (int rr = 0; rr < 4; ++rr)
        C[(size_t)(row + rr) * N + col] = acc[mi][ni][rr];
    }
  }
}

// ---------------- flash attention: counted-vmcnt 3-buffer pipeline ---------
__global__ __launch_bounds__(256, 2)
void attn_kernel(const u16* __restrict__ Qh, const u16* __restrict__ Kh,
                 const u16* __restrict__ Vt, u16* __restrict__ attnO) {
  __shared__ __align__(16) u16 lds[3][8192];  // per buf: K[0:4096] V[4096:8192]
  const int tid = threadIdx.x, lane = tid & 63, w = tid >> 6;
  const int bid = blockIdx.x;
  const int x = bid & 7, j = bid >> 3;
  const int half = j >> 5, jj = j & 31;
  const int bh = (x << 2) + (jj >> 4) + (half << 1);  // 4 bh per XCD
  const int r = jj & 15;
  const int qt = half ? r : 15 - r;                    // CU pair sums to 15
  const int h = bh & 15, b = bh >> 4;

  const int qi = lane & 31, hi = lane >> 5;
  const int q0 = (qt << 7) + (w << 5);
  const int qabs = q0 + qi;

  const u16* Qp = Qh + (size_t)(b * 16 + h) * 262144;
  const u16* Kp = Kh + (size_t)(b * 16 + h) * 262144;
  const u16* Vp = Vt + (size_t)((b << 2) + (h >> 2)) * 262144;

  bf16x8 qf[8];
#pragma unroll
  for (int kc = 0; kc < 8; ++kc)
    qf[kc] = *(const bf16x8*)&Qp[(size_t)qabs * 128 + kc * 16 + hi * 8];

  const int kRow = tid >> 4;
  const int kCl = ((tid & 15) ^ (kRow & 7)) << 3;
  const int vRow = tid >> 2;
  const int vCl = ((tid & 3) ^ ((tid >> 3) & 3)) << 3;
  const int ldsoff = tid << 3;

  f32x16 ot[4] = {};
  float mrow = -1e30f, lsum = 0.f;
  const int nt = (qt << 2) + 4;
  const int nt_w = (qt << 2) + w + 1;
  const int swq = qi & 7, swv = (qi >> 1) & 3;

#pragma unroll
  for (int pt = 0; pt < 2; ++pt) {
    u16* bb = (u16*)lds[pt];
    gld_lds16(Kp + (size_t)((pt << 5) + kRow) * 128 + kCl, bb + ldsoff);
    gld_lds16(Kp + (size_t)((pt << 5) + kRow + 16) * 128 + kCl, bb + ldsoff + 2048);
    gld_lds16(Vp + (size_t)vRow * 2048 + (pt << 5) + vCl, bb + 4096 + ldsoff);
    gld_lds16(Vp + (size_t)(vRow + 64) * 2048 + (pt << 5) + vCl, bb + 4096 + ldsoff + 2048);
  }

  int bufc = 0;
  for (int t = 0; t < nt; ++t) {
    asm volatile("s_waitcnt vmcnt(4)" ::: "memory");
    __builtin_amdgcn_sched_barrier(0);
    __builtin_amdgcn_s_barrier();
    {
      const int ts = (t + 2 < nt) ? t + 2 : nt - 1;
      const int bufn = bufc ? bufc - 1 : 2;
      u16* bb = (u16*)lds[bufn];
      gld_lds16(Kp + (size_t)((ts << 5) + kRow) * 128 + kCl, bb + ldsoff);
      gld_lds16(Kp + (size_t)((ts << 5) + kRow + 16) * 128 + kCl, bb + ldsoff + 2048);
      gld_lds16(Vp + (size_t)vRow * 2048 + (ts << 5) + vCl, bb + 4096 + ldsoff);
      gld_lds16(Vp + (size_t)(vRow + 64) * 2048 + (ts << 5) + vCl, bb + 4096 + ldsoff + 2048);
    }
    if (t < nt_w) {
      const u16* kb_ = &lds[bufc][0];
      const u16* vb_ = &lds[bufc][4096];
      f32x16 st = {};
      __builtin_amdgcn_s_setprio(1);
#pragma unroll
      for (int kc = 0; kc < 8; ++kc) {
        bf16x8 kf = *(const bf16x8*)&kb_[(qi << 7) + ((((kc << 1) + hi) ^ swq) << 3)];
        st = mfma32(kf, qf[kc], st);
      }
      __builtin_amdgcn_s_setprio(0);

      if (t == nt_w - 1) {  // diagonal tile
        const int kb0 = t << 5;
#pragma unroll
        for (int reg = 0; reg < 16; ++reg) {
          int kk = kb0 + (reg & 3) + ((reg >> 2) << 3) + (hi << 2);
          if (kk > qabs) st[reg] = -1e30f;
        }
      }

      float tmax = st[0];
#pragma unroll
      for (int reg = 1; reg < 16; ++reg) tmax = fmaxf(tmax, st[reg]);
      tmax = fmaxf(tmax, __shfl_xor(tmax, 32));

      if (__any(tmax - mrow > 11.5f)) {  // defer-max, log2 units
        float nm = fmaxf(mrow, tmax);
        float al = __builtin_amdgcn_exp2f(mrow - nm);
        mrow = nm;
        lsum *= al;
#pragma unroll
        for (int db = 0; db < 4; ++db)
#pragma unroll
          for (int reg = 0; reg < 16; ++reg) ot[db][reg] *= al;
      }

      float psum = 0.f;
#pragma unroll
      for (int reg = 0; reg < 16; ++reg) {
        st[reg] = __builtin_amdgcn_exp2f(st[reg] - mrow);
        psum += st[reg];
      }
      psum += __shfl_xor(psum, 32);
      lsum += psum;

      bf16x8 pfrag[2];
#pragma unroll
      for (int bbp = 0; bbp < 2; ++bbp) {
        unsigned x0 = pk2(st[8 * bbp + 0], st[8 * bbp + 1]);
        unsigned x1 = pk2(st[8 * bbp + 2], st[8 * bbp + 3]);
        unsigned y0 = pk2(st[8 * bbp + 4], st[8 * bbp + 5]);
        unsigned y1 = pk2(st[8 * bbp + 6], st[8 * bbp + 7]);
        asm("v_permlane32_swap_b32 %0, %1" : "+v"(x0), "+v"(y0));
        asm("v_permlane32_swap_b32 %0, %1" : "+v"(x1), "+v"(y1));
        u32x4 uw = { x0, x1, y0, y1 };
        pfrag[bbp] = __builtin_bit_cast(bf16x8, uw);
      }

      __builtin_amdgcn_s_setprio(1);
#pragma unroll
      for (int db = 0; db < 4; ++db) {
        const u16* vr = &vb_[((db << 5) + qi) << 5];
#pragma unroll
        for (int ks = 0; ks < 2; ++ks) {
          bf16x8 vf = *(const bf16x8*)&vr[((((ks << 1) + hi)) ^ swv) << 3];
          ot[db] = mfma32(vf, pfrag[ks], ot[db]);
        }
      }
      __builtin_amdgcn_s_setprio(0);
    }
    bufc = (bufc == 2) ? 0 : bufc + 1;
  }

  float inv = 1.f / lsum;
  u16* rowp = attnO + (size_t)(b * 2048 + qabs) * 2048 + h * 128 + (hi << 2);
#pragma unroll
  for (int db = 0; db < 4; ++db)
#pragma unroll
    for (int mg = 0; mg < 4; ++mg) {
      u16x4 pkv = { f2b(ot[db][4 * mg + 0] * inv), f2b(ot[db][4 * mg + 1] * inv),
                    f2b(ot[db][4 * mg + 2] * inv), f2b(ot[db][4 * mg + 3] * inv) };
      *(u16x4*)&rowp[(db << 5) + (mg << 3)] = pkv;
    }
}

// ---------------------------------------------------------------------------
extern "C" void kernel_launch(void* const* d_in, const int* in_sizes, int n_in,
                              void* d_out, int out_size, void* d_ws, size_t ws_size,
                              hipStream_t stream) {
  const float* x  = (const float*)d_in[0];
  const float* Wq = (const float*)d_in[1];
  const float* Wk = (const float*)d_in[2];
  const float* Wv = (const float*)d_in[3];
  const float* Wo = (const float*)d_in[4];
  float* out = (float*)d_out;
  char* ws = (char*)d_ws;

  u16*      xb   = (u16*)(ws + 0);            // 16 MB
  u16*      wqb  = (u16*)(ws + 16777216);     //  8 MB
  u16*      wkb  = (u16*)(ws + 25165824);     //  2 MB
  u16*      wvb  = (u16*)(ws + 27262976);     //  2 MB
  u16*      wob  = (u16*)(ws + 29360128);     //  8 MB
  unsigned* csT  = (unsigned*)(ws + 37748736);//  8 MB (packed bf16 pairs)
  u16*      Qhp  = (u16*)(ws + 54525952);     // 16 MB
  u16*      Khp  = (u16*)(ws + 71303168);     // 16 MB
  u16*      Vtp  = (u16*)(ws + 88080384);     //  4 MB
  u16*      attnb= (u16*)(ws + 92274688);     // 16 MB

  prep<<<26624, 256, 0, stream>>>((const float4*)x, (const float4*)Wq,
                                  (const float4*)Wk, (const float4*)Wv,
                                  (const float4*)Wo, (u16x4*)xb, (u16x4*)wqb,
                                  (u16x4*)wkb, (u16x4*)wvb, (u16x4*)wob, csT);
  gemm_qkv<<<dim3(12, 16), 512, 0, stream>>>(xb, wqb, wkb, wvb, csT, Qhp, Khp, Vtp);
  attn_kernel<<<512, 256, 0, stream>>>(Qhp, Khp, Vtp, attnb);
  gemm_bt<<<dim3(16, 32), 256, 0, stream>>>(attnb, wob, out, 4096, 2048, 2048);
}